// Round 1
// baseline (9756.274 us; speedup 1.0000x reference)
//
#include <hip/hip_runtime.h>

// VQ-VAE EMA vector quantizer, fp32.
// N=65536 rows (32*2048), D=256, K=1024 codes.
// Outputs (flat concat): z_q_st [N*D], vq_loss [1], codes [N] (as float),
//                        new_embedding [K*D], new_cluster_size [K], new_embed_avg [K*D]

#define DDIM 256
#define DQ   64      // DDIM/4
#define KC   1024
#define BM   128     // rows per block
#define BN   128     // codes per k-tile
#define BD   32      // d-chunk
#define LS   36      // LDS row stride in floats: 36%32==4 (2-way max aliasing), 144B %16==0 (b128-aligned)
#define DECAYF 0.99f
#define OMDF   0.01f
#define BETAF  0.25f
#define EPSF   1e-5f

__global__ __launch_bounds__(256, 2) void vq_main(
    const float* __restrict__ z,         // [N, D]
    const float* __restrict__ emb,       // [K, D]
    float* __restrict__ out_zq,          // [N, D]
    float* __restrict__ out_codes,       // [N] (float-encoded ints)
    float* __restrict__ embed_sum,       // ws [K*D], pre-zeroed
    float* __restrict__ counts,          // ws [K],  pre-zeroed
    float* __restrict__ loss_acc)        // ws [1],  pre-zeroed
{
    __shared__ float zs[BM * LS];        // 18432 B
    __shared__ float es[BN * LS];        // 18432 B
    __shared__ float esq_s[KC];          // 4096 B
    __shared__ float zsq_s[BM];          // 512 B
    __shared__ float red_v[BM * 16];     // 8192 B
    __shared__ int   red_i[BM * 16];     // 8192 B
    __shared__ int   codes_s[BM];        // 512 B
    __shared__ float lred[256];          // 1024 B   -> total ~59.4 KB

    const int tid  = threadIdx.x;
    const int row0 = blockIdx.x * BM;
    const int trow = tid >> 4;           // 0..15
    const int tcol = tid & 15;           // 0..15

    // ---- prologue: ||e||^2 for all K codes, ||z||^2 for block rows ----
    for (int k = tid; k < KC; k += 256) {
        const float4* ep = (const float4*)(emb + (size_t)k * DDIM);
        float s = 0.f;
        for (int q = 0; q < DQ; ++q) {
            float4 v = ep[q];
            s += v.x * v.x + v.y * v.y + v.z * v.z + v.w * v.w;
        }
        esq_s[k] = s;
    }
    if (tid < BM) {
        const float4* zp = (const float4*)(z + (size_t)(row0 + tid) * DDIM);
        float s = 0.f;
        for (int q = 0; q < DQ; ++q) {
            float4 v = zp[q];
            s += v.x * v.x + v.y * v.y + v.z * v.z + v.w * v.w;
        }
        zsq_s[tid] = s;
    }

    float runv[8];
    int   runi[8];
#pragma unroll
    for (int i = 0; i < 8; ++i) { runv[i] = 3.4e38f; runi[i] = 0; }

    for (int kt = 0; kt < KC / BN; ++kt) {
        float acc[8][8];
#pragma unroll
        for (int i = 0; i < 8; ++i)
#pragma unroll
            for (int j = 0; j < 8; ++j) acc[i][j] = 0.f;

        for (int dc = 0; dc < DDIM / BD; ++dc) {
            __syncthreads();
            // stage z-chunk [128 x 32] and e-chunk [128 x 32]
#pragma unroll
            for (int it = 0; it < 4; ++it) {
                int chunk = tid + it * 256;     // 0..1023
                int r = chunk >> 3;
                int q = chunk & 7;
                float4 zv = *(const float4*)(z + (size_t)(row0 + r) * DDIM + dc * BD + q * 4);
                *(float4*)(zs + r * LS + q * 4) = zv;
                float4 ev = *(const float4*)(emb + (size_t)(kt * BN + r) * DDIM + dc * BD + q * 4);
                *(float4*)(es + r * LS + q * 4) = ev;
            }
            __syncthreads();
#pragma unroll
            for (int q = 0; q < BD / 4; ++q) {
                float4 a[8], b[8];
#pragma unroll
                for (int i = 0; i < 8; ++i)
                    a[i] = *(const float4*)(zs + (trow + 16 * i) * LS + q * 4);
#pragma unroll
                for (int j = 0; j < 8; ++j)
                    b[j] = *(const float4*)(es + (tcol + 16 * j) * LS + q * 4);
#pragma unroll
                for (int i = 0; i < 8; ++i)
#pragma unroll
                    for (int j = 0; j < 8; ++j)
                        acc[i][j] += a[i].x * b[j].x + a[i].y * b[j].y +
                                     a[i].z * b[j].z + a[i].w * b[j].w;
            }
        }

        // fold this k-tile into the running argmin (cols scanned ascending)
#pragma unroll
        for (int i = 0; i < 8; ++i) {
            float zq2 = zsq_s[trow + 16 * i];
#pragma unroll
            for (int j = 0; j < 8; ++j) {
                int col = kt * BN + tcol + 16 * j;
                float dist = zq2 - 2.f * acc[i][j] + esq_s[col];
                if (dist < runv[i]) { runv[i] = dist; runi[i] = col; }
            }
        }
    }

    // ---- cross-thread argmin combine (16 col-threads per row) ----
#pragma unroll
    for (int i = 0; i < 8; ++i) {
        int lr = trow + 16 * i;
        red_v[lr * 16 + tcol] = runv[i];
        red_i[lr * 16 + tcol] = runi[i];
    }
    __syncthreads();
    if (tid < BM) {
        float bv = red_v[tid * 16];
        int   bi = red_i[tid * 16];
        for (int t = 1; t < 16; ++t) {
            float v  = red_v[tid * 16 + t];
            int   ix = red_i[tid * 16 + t];
            if (v < bv || (v == bv && ix < bi)) { bv = v; bi = ix; }
        }
        codes_s[tid] = bi;
        out_codes[row0 + tid] = (float)bi;
        atomicAdd(&counts[bi], 1.0f);
    }
    __syncthreads();

    // ---- epilogue: gather z_q, write z_q_st, commit-loss partial, scatter embed_sum ----
    const int wave = tid >> 6;
    const int lane = tid & 63;
    float lp = 0.f;
    for (int r = wave; r < BM; r += 4) {
        int code = codes_s[r];
        float4 e4 = *(const float4*)(emb + (size_t)code * DDIM + lane * 4);
        float4 z4 = *(const float4*)(z + (size_t)(row0 + r) * DDIM + lane * 4);
        float dx = e4.x - z4.x, dy = e4.y - z4.y, dz = e4.z - z4.z, dw = e4.w - z4.w;
        float4 o;
        o.x = z4.x + dx; o.y = z4.y + dy; o.z = z4.z + dz; o.w = z4.w + dw;  // z_e + (z_q - z_e)
        *(float4*)(out_zq + (size_t)(row0 + r) * DDIM + lane * 4) = o;
        lp += dx * dx + dy * dy + dz * dz + dw * dw;                         // (z_e - z_q)^2
        float* esr = embed_sum + (size_t)code * DDIM + lane * 4;
        atomicAdd(esr + 0, z4.x);
        atomicAdd(esr + 1, z4.y);
        atomicAdd(esr + 2, z4.z);
        atomicAdd(esr + 3, z4.w);
    }
    lred[tid] = lp;
    __syncthreads();
    for (int s = 128; s > 0; s >>= 1) {
        if (tid < s) lred[tid] += lred[tid + s];
        __syncthreads();
    }
    if (tid == 0) atomicAdd(loss_acc, lred[0]);
}

__global__ void vq_finalize(const float* __restrict__ cluster_size,
                            const float* __restrict__ counts,
                            const float* __restrict__ loss_acc,
                            float* __restrict__ out_ncs,
                            float* __restrict__ out_loss,
                            float* __restrict__ cs_sm,
                            float inv_ND)
{
    __shared__ float sred[KC];
    const int tid = threadIdx.x;
    float ncs = cluster_size[tid] * DECAYF + counts[tid] * OMDF;
    out_ncs[tid] = ncs;
    sred[tid] = ncs;
    __syncthreads();
    for (int s = KC / 2; s > 0; s >>= 1) {
        if (tid < s) sred[tid] += sred[tid + s];
        __syncthreads();
    }
    float n = sred[0];
    cs_sm[tid] = (ncs + EPSF) / (n + (float)KC * EPSF) * n;
    if (tid == 0) out_loss[0] = BETAF * loss_acc[0] * inv_ND;
}

__global__ void vq_embed(const float* __restrict__ embed_avg,
                         const float* __restrict__ embed_sum,
                         const float* __restrict__ cs_sm,
                         float* __restrict__ out_nea,
                         float* __restrict__ out_nemb)
{
    int idx = blockIdx.x * blockDim.x + threadIdx.x;   // float4 index
    int k = idx >> 6;                                   // 64 float4 per code row
    float4 ea = ((const float4*)embed_avg)[idx];
    float4 s4 = ((const float4*)embed_sum)[idx];
    float4 nea;
    nea.x = ea.x * DECAYF + s4.x * OMDF;
    nea.y = ea.y * DECAYF + s4.y * OMDF;
    nea.z = ea.z * DECAYF + s4.z * OMDF;
    nea.w = ea.w * DECAYF + s4.w * OMDF;
    ((float4*)out_nea)[idx] = nea;
    float cs = cs_sm[k];
    float4 ne;
    ne.x = nea.x / cs; ne.y = nea.y / cs; ne.z = nea.z / cs; ne.w = nea.w / cs;
    ((float4*)out_nemb)[idx] = ne;
}

extern "C" void kernel_launch(void* const* d_in, const int* in_sizes, int n_in,
                              void* d_out, int out_size, void* d_ws, size_t ws_size,
                              hipStream_t stream) {
    const float* z            = (const float*)d_in[0];   // [N, 256]
    const float* emb          = (const float*)d_in[1];   // [1024, 256]
    const float* cluster_size = (const float*)d_in[2];   // [1024]
    const float* embed_avg    = (const float*)d_in[3];   // [1024, 256]

    const int ND = in_sizes[0];       // N*D = 16777216
    const int KD = in_sizes[1];       // K*D = 262144
    const int K  = in_sizes[2];       // 1024
    const int N  = ND / DDIM;         // 65536

    float* out       = (float*)d_out;
    float* out_zq    = out;                              // [N*D]
    float* out_loss  = out + (size_t)ND;                 // [1]
    float* out_codes = out + (size_t)ND + 1;             // [N]
    float* out_nemb  = out + (size_t)ND + 1 + N;         // [K*D]
    float* out_ncs   = out_nemb + (size_t)KD;            // [K]
    float* out_nea   = out_ncs + (size_t)K;              // [K*D]

    float* ws        = (float*)d_ws;
    float* embed_sum = ws;                 // [K*D]
    float* counts    = ws + (size_t)KD;    // [K]
    float* loss_acc  = counts + K;         // [1]
    float* cs_sm     = loss_acc + 1;       // [K]

    hipMemsetAsync(d_ws, 0, (size_t)(KD + K + 1) * sizeof(float), stream);
    vq_main<<<N / BM, 256, 0, stream>>>(z, emb, out_zq, out_codes,
                                        embed_sum, counts, loss_acc);
    vq_finalize<<<1, K, 0, stream>>>(cluster_size, counts, loss_acc,
                                     out_ncs, out_loss, cs_sm, 1.0f / (float)ND);
    vq_embed<<<KD / 1024, 256, 0, stream>>>(embed_avg, embed_sum, cs_sm,
                                            out_nea, out_nemb);
}